// Round 10
// baseline (228.175 us; speedup 1.0000x reference)
//
#include <hip/hip_runtime.h>

#define BATCH 8
#define NN 4096
#define DD 512
#define KK 2048
#define NCHUNK 32
#define SPLIT 16
#define JSPLIT 8
#define JCH (NN / JSPLIT)             // 512
#define ADJ_UNITS (BATCH * KK)                        // 16384
#define H_UNITS (BATCH * KK * (DD / 4) / 256)         // 8192
#define GATHER_GRID 2048

typedef float v4f __attribute__((ext_vector_type(4)));

// ----- col_sum: R4 partial shape + LDS combine + hw f64 atomics (no reduce) --
__global__ __launch_bounds__(512) void colsum_kernel(
    const float* __restrict__ h, double* __restrict__ colsum) {
    __shared__ double red[4][DD];
    int b = blockIdx.x / NCHUNK;
    int c = blockIdx.x % NCHUNK;
    int c4 = threadIdx.x & 127;   // float4 column
    int rr = threadIdx.x >> 7;    // row stream 0..3
    const float4* hp = (const float4*)h +
        ((size_t)(b * NN + c * 128)) * (DD / 4) + c4;
    double a0 = 0, a1 = 0, a2 = 0, a3 = 0;
    #pragma unroll 4
    for (int n = rr; n < 128; n += 4) {
        float4 v = hp[(size_t)n * (DD / 4)];
        a0 += v.x; a1 += v.y; a2 += v.z; a3 += v.w;
    }
    red[rr][c4 * 4 + 0] = a0;
    red[rr][c4 * 4 + 1] = a1;
    red[rr][c4 * 4 + 2] = a2;
    red[rr][c4 * 4 + 3] = a3;
    __syncthreads();
    if (rr == 0) {
        #pragma unroll
        for (int q = 0; q < 4; ++q) {
            int d = c4 * 4 + q;
            double s = red[0][d] + red[1][d] + red[2][d] + red[3][d];
            unsafeAtomicAdd(&colsum[b * DD + d], s);   // global_atomic_add_f64
        }
    }
}

// ---------------- scores: one wave (64 lanes) per row (R4 exact) -------------
__global__ __launch_bounds__(256) void scores_kernel(
    const float* __restrict__ h, const double* __restrict__ colsum,
    float* __restrict__ scores) {
    int wave = threadIdx.x >> 6;
    int lane = threadIdx.x & 63;
    int r = blockIdx.x * 4 + wave;            // global row in [0, BATCH*NN)
    int b = r >> 12;                          // r / NN
    const float4* hp = (const float4*)(h + (size_t)r * DD) + lane * 2;
    float4 v0 = hp[0];
    float4 v1 = hp[1];
    const double* cs = colsum + b * DD + lane * 8;
    double acc = (double)v0.x * cs[0] + (double)v0.y * cs[1] +
                 (double)v0.z * cs[2] + (double)v0.w * cs[3] +
                 (double)v1.x * cs[4] + (double)v1.y * cs[5] +
                 (double)v1.z * cs[6] + (double)v1.w * cs[7];
    #pragma unroll
    for (int off = 32; off >= 1; off >>= 1) acc += __shfl_down(acc, off);
    if (lane == 0) scores[r] = (float)acc;
}

// ------ count + compact fused via last-block ticket per batch ----------------
__global__ __launch_bounds__(256) void count_compact_kernel(
    const float* __restrict__ scores, int* __restrict__ pcount,
    int* __restrict__ tickets, int* __restrict__ idx) {
    __shared__ float sc[JCH];
    __shared__ int wtot[4];
    __shared__ int is_last;
    int blk = blockIdx.x;
    int jc = blk % JSPLIT;
    int s  = (blk / JSPLIT) % SPLIT;
    int b  = blk / (JSPLIT * SPLIT);
    int t = threadIdx.x;

    // ---- count phase (R4 body) ----
    const float* srow = scores + b * NN;
    for (int j = t; j < JCH; j += 256) sc[j] = srow[jc * JCH + j];
    __syncthreads();
    {
        int i = s * 256 + t;
        float si = srow[i];
        int jbase = jc * JCH;
        int cnt = 0;
        const float4* sc4 = (const float4*)sc;
        #pragma unroll 4
        for (int jj = 0; jj < JCH / 4; ++jj) {
            float4 sv = sc4[jj];
            int j0 = jbase + jj * 4;
            cnt += (sv.x < si || (sv.x == si && (j0 + 0) < i)) ? 1 : 0;
            cnt += (sv.y < si || (sv.y == si && (j0 + 1) < i)) ? 1 : 0;
            cnt += (sv.z < si || (sv.z == si && (j0 + 2) < i)) ? 1 : 0;
            cnt += (sv.w < si || (sv.w == si && (j0 + 3) < i)) ? 1 : 0;
        }
        pcount[((size_t)jc * BATCH + b) * NN + i] = cnt;
    }
    __threadfence();                 // release: make this thread's store device-visible
    __syncthreads();
    if (t == 0) {
        int old = atomicAdd(&tickets[b], 1);
        is_last = (old == SPLIT * JSPLIT - 1);
    }
    __syncthreads();
    if (!is_last) return;

    // ---- compact phase: this block is last for batch b ----
    __threadfence();                 // acquire: read fresh pcount across XCDs
    int lane = t & 63, w = t >> 6;
    unsigned mask = 0;
    #pragma unroll
    for (int q = 0; q < 16; ++q) {
        int i = t * 16 + q;
        int cnt = 0;
        #pragma unroll
        for (int c = 0; c < JSPLIT; ++c)
            cnt += pcount[((size_t)c * BATCH + b) * NN + i];
        if (cnt < KK) mask |= (1u << q);
    }
    int local = __popc(mask);
    int scan = local;
    #pragma unroll
    for (int off = 1; off < 64; off <<= 1) {
        int x = __shfl_up(scan, off);
        if (lane >= off) scan += x;
    }
    if (lane == 63) wtot[w] = scan;
    __syncthreads();
    int wbase = 0;
    for (int ww = 0; ww < w; ++ww) wbase += wtot[ww];
    int p = wbase + scan - local;
    int* irow = idx + b * KK;
    #pragma unroll
    for (int q = 0; q < 16; ++q) {
        if ((mask >> q) & 1) irow[p++] = t * 16 + q;
    }
}

// ------- gather: R4 exact — grid-stride, NT loads (adj) + NT stores ----------
__global__ __launch_bounds__(256) void gather_kernel(
    const float* __restrict__ h, const float* __restrict__ adj,
    const int* __restrict__ idx, float* __restrict__ out_h,
    float* __restrict__ out_adj) {
    for (int u = blockIdx.x; u < ADJ_UNITS + H_UNITS; u += GATHER_GRID) {
        if (u < ADJ_UNITS) {
            int row = u;                        // b*K + k
            int b = row >> 11;
            int src = idx[row];
            const v4f* ap = (const v4f*)adj + ((size_t)b * NN + src) * (NN / 4);
            v4f* op = (v4f*)out_adj + (size_t)row * (NN / 4);
            #pragma unroll
            for (int q = 0; q < 4; ++q) {
                int v = threadIdx.x + q * 256;
                v4f val = __builtin_nontemporal_load(ap + v);
                __builtin_nontemporal_store(val, op + v);
            }
        } else {
            int tid = (u - ADJ_UNITS) * 256 + threadIdx.x;  // float4 idx
            int v = tid & 127;
            int row = tid >> 7;
            int b = row >> 11;
            int src = idx[row];
            v4f val = ((const v4f*)h)[((size_t)b * NN + src) * (DD / 4) + v];
            __builtin_nontemporal_store(val, (v4f*)out_h + tid);
        }
    }
}

extern "C" void kernel_launch(void* const* d_in, const int* in_sizes, int n_in,
                              void* d_out, int out_size, void* d_ws, size_t ws_size,
                              hipStream_t stream) {
    const float* h   = (const float*)d_in[0];
    const float* adj = (const float*)d_in[1];
    float* out = (float*)d_out;
    char* ws = (char*)d_ws;

    double* colsum  = (double*)ws;                 // 32 KiB  @ 0
    int*    tickets = (int*)(ws + 32768);          // 128 B   @ 32768
    float*  scores  = (float*)(ws + 65536);        // 128 KiB @ 65536
    int*    pcount  = (int*)(ws + 65536 + 131072); // 1 MiB
    int*    idx     = (int*)(ws + 65536 + 131072 + 1048576); // 64 KiB

    // zero colsum (atomic accumulator) + tickets, every call (graph-safe memset node)
    hipMemsetAsync(ws, 0, 32768 + 128, stream);

    hipLaunchKernelGGL(colsum_kernel, dim3(BATCH * NCHUNK), dim3(512), 0, stream, h, colsum);
    hipLaunchKernelGGL(scores_kernel, dim3(BATCH * NN / 4), dim3(256), 0, stream, h, colsum, scores);
    hipLaunchKernelGGL(count_compact_kernel, dim3(BATCH * SPLIT * JSPLIT), dim3(256), 0, stream,
                       scores, pcount, tickets, idx);
    hipLaunchKernelGGL(gather_kernel, dim3(GATHER_GRID), dim3(256), 0, stream,
                       h, adj, idx, out, out + (size_t)BATCH * KK * DD);
}

// Round 11
// 162.346 us; speedup vs baseline: 1.4055x; 1.4055x over previous
//
#include <hip/hip_runtime.h>

#define BATCH 8
#define NN 4096
#define DD 512
#define KK 2048
#define NCHUNK 32
#define ROWS_PER_CHUNK (NN / NCHUNK)  // 128
#define SPLIT 16
#define JSPLIT 8
#define JCH (NN / JSPLIT)             // 512
#define GBLOCKS 2048

typedef float v4f __attribute__((ext_vector_type(4)));

// ---------------- col_sum partial: float4 loads, 4 row-streams per block -----
__global__ __launch_bounds__(512) void colsum_partial_kernel(
    const float* __restrict__ h, double* __restrict__ partial) {
    int b = blockIdx.x / NCHUNK;
    int c = blockIdx.x % NCHUNK;
    int c4 = threadIdx.x & 127;   // float4 column
    int rr = threadIdx.x >> 7;    // row stream 0..3
    const float4* hp = (const float4*)h +
        ((size_t)(b * NN + c * ROWS_PER_CHUNK)) * (DD / 4) + c4;
    double a0 = 0, a1 = 0, a2 = 0, a3 = 0;
    #pragma unroll 4
    for (int n = rr; n < ROWS_PER_CHUNK; n += 4) {
        float4 v = hp[(size_t)n * (DD / 4)];
        a0 += v.x; a1 += v.y; a2 += v.z; a3 += v.w;
    }
    double* pp = partial + (((size_t)(b * NCHUNK + c) * 4 + rr) * DD) + c4 * 4;
    pp[0] = a0; pp[1] = a1; pp[2] = a2; pp[3] = a3;
}

__global__ __launch_bounds__(512) void colsum_reduce_kernel(
    const double* __restrict__ partial, double* __restrict__ colsum) {
    int b = blockIdx.x;
    int d = threadIdx.x;
    double acc = 0.0;
    #pragma unroll 8
    for (int q = 0; q < NCHUNK * 4; ++q)
        acc += partial[((size_t)b * NCHUNK * 4 + q) * DD + d];
    colsum[b * DD + d] = acc;
}

// ---------------- scores: one wave (64 lanes) per row ------------------------
__global__ __launch_bounds__(256) void scores_kernel(
    const float* __restrict__ h, const double* __restrict__ colsum,
    float* __restrict__ scores) {
    int wave = threadIdx.x >> 6;
    int lane = threadIdx.x & 63;
    int r = blockIdx.x * 4 + wave;            // global row in [0, BATCH*NN)
    int b = r >> 12;                          // r / NN
    const float4* hp = (const float4*)(h + (size_t)r * DD) + lane * 2;
    float4 v0 = hp[0];
    float4 v1 = hp[1];
    const double* cs = colsum + b * DD + lane * 8;
    double acc = (double)v0.x * cs[0] + (double)v0.y * cs[1] +
                 (double)v0.z * cs[2] + (double)v0.w * cs[3] +
                 (double)v1.x * cs[4] + (double)v1.y * cs[5] +
                 (double)v1.z * cs[6] + (double)v1.w * cs[7];
    #pragma unroll
    for (int off = 32; off >= 1; off >>= 1) acc += __shfl_down(acc, off);
    if (lane == 0) scores[r] = (float)acc;
}

// ---------------- partial rank counts: j-range split 8-way, float4 LDS -------
__global__ __launch_bounds__(256) void count_kernel(
    const float* __restrict__ scores, int* __restrict__ pcount) {
    __shared__ float sc[JCH];
    int blk = blockIdx.x;
    int jc = blk % JSPLIT;
    int s  = (blk / JSPLIT) % SPLIT;
    int b  = blk / (JSPLIT * SPLIT);
    const float* srow = scores + b * NN;
    for (int j = threadIdx.x; j < JCH; j += 256) sc[j] = srow[jc * JCH + j];
    __syncthreads();
    int i = s * 256 + threadIdx.x;
    float si = srow[i];
    int jbase = jc * JCH;
    int cnt = 0;
    const float4* sc4 = (const float4*)sc;
    #pragma unroll 4
    for (int jj = 0; jj < JCH / 4; ++jj) {
        float4 sv = sc4[jj];
        int j0 = jbase + jj * 4;
        cnt += (sv.x < si || (sv.x == si && (j0 + 0) < i)) ? 1 : 0;
        cnt += (sv.y < si || (sv.y == si && (j0 + 1) < i)) ? 1 : 0;
        cnt += (sv.z < si || (sv.z == si && (j0 + 2) < i)) ? 1 : 0;
        cnt += (sv.w < si || (sv.w == si && (j0 + 3) < i)) ? 1 : 0;
    }
    pcount[((size_t)jc * BATCH + b) * NN + i] = cnt;
}

// ---------------- compact: combine partial counts -> flags -> index list -----
__global__ __launch_bounds__(1024) void compact_kernel(
    const int* __restrict__ pcount, int* __restrict__ idx) {
    __shared__ int wtot[16];
    int b = blockIdx.x;
    int t = threadIdx.x;
    int lane = t & 63, w = t >> 6;
    int f[4];
    #pragma unroll
    for (int q = 0; q < 4; ++q) {
        int i = t * 4 + q;
        int cnt = 0;
        #pragma unroll
        for (int jc = 0; jc < JSPLIT; ++jc)
            cnt += pcount[((size_t)jc * BATCH + b) * NN + i];
        f[q] = (cnt < KK) ? 1 : 0;
    }
    int local = f[0] + f[1] + f[2] + f[3];
    int scan = local;
    #pragma unroll
    for (int off = 1; off < 64; off <<= 1) {
        int x = __shfl_up(scan, off);
        if (lane >= off) scan += x;
    }
    if (lane == 63) wtot[w] = scan;
    __syncthreads();
    int wbase = 0;
    for (int ww = 0; ww < w; ++ww) wbase += wtot[ww];
    int p = wbase + scan - local;
    int* irow = idx + b * KK;
    #pragma unroll
    for (int q = 0; q < 4; ++q) {
        if (f[q]) irow[p++] = t * 4 + q;
    }
}

// ---- gather: R4 structure + interleaved adj/h units (AAH pattern) -----------
// Per block: 8 adj units (16 KB row each) + 4 h units (256 float4 each),
// interleaved so the L3-hot h reads overlap the HBM-bound adj stream
// instead of forming a serial tail. NT loads on adj, NT stores on both.
__global__ __launch_bounds__(256) void gather_kernel(
    const float* __restrict__ h, const float* __restrict__ adj,
    const int* __restrict__ idx, float* __restrict__ out_h,
    float* __restrict__ out_adj) {
    int blk = blockIdx.x;
    int t = threadIdx.x;
    const v4f* adj4 = (const v4f*)adj;
    const v4f* h4 = (const v4f*)h;
    v4f* oa4 = (v4f*)out_adj;
    v4f* oh4 = (v4f*)out_h;
    #pragma unroll
    for (int it = 0; it < 12; ++it) {
        if (it % 3 != 2) {
            // adj unit a = it - it/3  (0..7)
            int a = it - it / 3;
            int row = blk + a * GBLOCKS;        // b*K + k
            int b = row >> 11;
            int src = idx[row];
            const v4f* ap = adj4 + ((size_t)b * NN + src) * (NN / 4);
            v4f* op = oa4 + (size_t)row * (NN / 4);
            #pragma unroll
            for (int q = 0; q < 4; ++q) {
                int v = t + q * 256;
                v4f val = __builtin_nontemporal_load(ap + v);
                __builtin_nontemporal_store(val, op + v);
            }
        } else {
            // h unit j = it/3  (0..3); unit covers 256 float4 = 2 h rows
            int j = it / 3;
            int u = blk + j * GBLOCKS;
            size_t tid = (size_t)u * 256 + t;
            int v = (int)(tid & 127);
            int row = (int)(tid >> 7);
            int b = row >> 11;
            int src = idx[row];
            v4f val = h4[((size_t)b * NN + src) * (DD / 4) + v];
            __builtin_nontemporal_store(val, oh4 + tid);
        }
    }
}

extern "C" void kernel_launch(void* const* d_in, const int* in_sizes, int n_in,
                              void* d_out, int out_size, void* d_ws, size_t ws_size,
                              hipStream_t stream) {
    const float* h   = (const float*)d_in[0];
    const float* adj = (const float*)d_in[1];
    float* out = (float*)d_out;
    char* ws = (char*)d_ws;

    double* partial = (double*)ws;                        // 4 MiB
    double* colsum  = (double*)(ws + 4194304);            // 32 KiB
    float*  scores  = (float*)(ws + 4194304 + 32768);     // 128 KiB
    int*    pcount  = (int*)(ws + 4194304 + 32768 + 131072);           // 1 MiB
    int*    idx     = (int*)(ws + 4194304 + 32768 + 131072 + 1048576); // 64 KiB

    hipLaunchKernelGGL(colsum_partial_kernel, dim3(BATCH * NCHUNK), dim3(512), 0, stream, h, partial);
    hipLaunchKernelGGL(colsum_reduce_kernel, dim3(BATCH), dim3(512), 0, stream, partial, colsum);
    hipLaunchKernelGGL(scores_kernel, dim3(BATCH * NN / 4), dim3(256), 0, stream, h, colsum, scores);
    hipLaunchKernelGGL(count_kernel, dim3(BATCH * SPLIT * JSPLIT), dim3(256), 0, stream, scores, pcount);
    hipLaunchKernelGGL(compact_kernel, dim3(BATCH), dim3(1024), 0, stream, pcount, idx);
    hipLaunchKernelGGL(gather_kernel, dim3(GBLOCKS), dim3(256), 0, stream,
                       h, adj, idx, out, out + (size_t)BATCH * KK * DD);
}